// Round 23
// baseline (9466.262 us; speedup 1.0000x reference)
//
#include <hip/hip_runtime.h>
#include <hip/hip_bf16.h>
#include <stdint.h>

typedef __bf16 bf16;
typedef __bf16 bf16x8 __attribute__((ext_vector_type(8)));
typedef __bf16 bf16x4 __attribute__((ext_vector_type(4)));
typedef float f32x4 __attribute__((ext_vector_type(4)));
typedef unsigned short u16;
typedef unsigned int u32;

constexpr int NB = 4;
constexpr int NT = 2048;
constexpr int NC = 2048;
constexpr int NH = 16;
constexpr int ND = 128;
constexpr int NC3 = 6144;

__device__ __forceinline__ void gload16(const void* g, void* l) {
  __builtin_amdgcn_global_load_lds((const __attribute__((address_space(1))) void*)g,
                                   (__attribute__((address_space(3))) void*)l, 16, 0, 0);
}

__device__ __forceinline__ u32 pack_bf16(float a, float b) {
  return (u32)__builtin_bit_cast(u16, (bf16)a) | ((u32)__builtin_bit_cast(u16, (bf16)b) << 16);
}

// ---------------- merged prep: mask decode | x ingest | W_qkv^T | W_proj^T ----------------
__global__ __launch_bounds__(256) void prep_k(const void* tok, char* maskC,
                                              const float* __restrict__ xr, bf16* __restrict__ xb,
                                              const float* __restrict__ wqkvr, bf16* __restrict__ wT,
                                              const float* __restrict__ wprojr, bf16* __restrict__ wpT) {
  __shared__ __align__(16) bf16 t[64][72];
  __shared__ int s_gt1, s_oddnz, s_allb, s_allf, s_allh;
  const int gid = blockIdx.x;
  const int tid = threadIdx.x;

  if (gid == 0) {
    if (tid == 0) { s_gt1 = 0; s_oddnz = 0; s_allb = 1; s_allf = 1; s_allh = 1; }
    __syncthreads();
    const unsigned int* mw = (const unsigned int*)tok;
    int gt1 = 0, oddnz = 0, allb = 1, allf = 1, allh = 1;
    for (int i = tid; i < 2048; i += 256) {
      unsigned v = mw[i];
      if (v > 1u) gt1 = 1;
      if ((i & 1) && v) oddnz = 1;
#pragma unroll
      for (int bb = 0; bb < 4; ++bb) { unsigned by = (v >> (8*bb)) & 0xffu; if (by > 1u) allb = 0; }
      if (v != 0u && v != 0x3F800000u) allf = 0;
      unsigned lo = v & 0xffffu, hi = v >> 16;
      if ((lo != 0u && lo != 0x3F80u) || (hi != 0u && hi != 0x3F80u)) allh = 0;
    }
    if (gt1) atomicOr(&s_gt1, 1);
    if (oddnz) atomicOr(&s_oddnz, 1);
    if (!allb) atomicAnd(&s_allb, 0);
    if (!allf) atomicAnd(&s_allf, 0);
    if (!allh) atomicAnd(&s_allh, 0);
    __syncthreads();
    int mode;
    if (!s_gt1)       mode = s_oddnz ? 0 : 2;
    else if (s_allf)  mode = 3;
    else if (s_allb)  mode = 1;
    else if (s_allh)  mode = 4;
    else              mode = 0;
    for (int i = tid; i < NB*NT; i += 256) {
      int v;
      if (mode == 0)      v = (((const int*)tok)[i] != 0);
      else if (mode == 1) v = (((const unsigned char*)tok)[i] != 0);
      else if (mode == 2) v = (((const long long*)tok)[i] != 0);
      else if (mode == 3) v = (((const unsigned int*)tok)[i] != 0);
      else                v = (((const unsigned short*)tok)[i] != 0);
      maskC[i] = (char)v;
    }
  } else if (gid < 8193) {
    long i = ((long)(gid - 1) * 256 + tid) * 8;
    f32x4 a = *(const f32x4*)(xr + i), b = *(const f32x4*)(xr + i + 4);
    bf16x8 o;
    o[0] = (bf16)a[0]; o[1] = (bf16)a[1]; o[2] = (bf16)a[2]; o[3] = (bf16)a[3];
    o[4] = (bf16)b[0]; o[5] = (bf16)b[1]; o[6] = (bf16)b[2]; o[7] = (bf16)b[3];
    *(bf16x8*)(xb + i) = o;
  } else {
    const float* in; bf16* out; int in_rs, out_rs, bx, by;
    if (gid < 11265) { int idx = gid - 8193; in = wqkvr; out = wT;  in_rs = NC3; out_rs = NC; bx = idx % 96; by = idx / 96; }
    else             { int idx = gid - 11265; in = wprojr; out = wpT; in_rs = NC;  out_rs = NC; bx = idx % 32; by = idx / 32; }
    const int r0 = by << 6, c0 = bx << 6;
#pragma unroll
    for (int i = 0; i < 4; ++i) {
      int slot = i*256 + tid, row = slot >> 4, c4 = slot & 15;
      f32x4 v = *(const f32x4*)(in + (long)(r0 + row)*in_rs + c0 + c4*4);
#pragma unroll
      for (int e = 0; e < 4; ++e) t[c4*4 + e][row] = (bf16)v[e];
    }
    __syncthreads();
#pragma unroll
    for (int i = 0; i < 2; ++i) {
      int slot = i*256 + tid, row = slot >> 3, c8 = slot & 7;
      bf16x8 v = *(const bf16x8*)(&t[row][c8*8]);
      *(bf16x8*)(out + (long)(c0 + row)*out_rs + r0 + c8*8) = v;
    }
  }
}

// ---------------- GEMM 256x256, 8 waves, 4-phase, spread-staged counted-vmcnt pipeline (r22) ----------------
#define G256_READ_A(qm_) \
  _Pragma("unroll") \
  for (int mi = 0; mi < 4; ++mi) { \
    _Pragma("unroll") \
    for (int kk = 0; kk < 2; ++kk) { \
      const int ri = (qm_)*64 + mi*16 + r; \
      af[mi*2+kk] = *(const bf16x8*)(Ac + wm*16384 + ri*128 + (((kk*4 + g) ^ (ri & 7)) << 4)); \
    } \
  }
#define G256_READ_B(qn_) \
  _Pragma("unroll") \
  for (int ni = 0; ni < 2; ++ni) { \
    _Pragma("unroll") \
    for (int kk = 0; kk < 2; ++kk) { \
      const int ri = (qn_)*32 + ni*16 + r; \
      bfr[ni*2+kk] = *(const bf16x8*)(Bc + wn*8192 + ri*128 + (((kk*4 + g) ^ (ri & 7)) << 4)); \
    } \
  }
#define G256_MFMA(mb_, nb_) \
  __builtin_amdgcn_s_setprio(1); \
  _Pragma("unroll") \
  for (int mi = 0; mi < 4; ++mi) \
    _Pragma("unroll") \
    for (int ni = 0; ni < 2; ++ni) \
      _Pragma("unroll") \
      for (int kk = 0; kk < 2; ++kk) \
        acc[(mb_)+mi][(nb_)+ni] = __builtin_amdgcn_mfma_f32_16x16x32_bf16(af[mi*2+kk], bfr[ni*2+kk], acc[(mb_)+mi][(nb_)+ni], 0, 0, 0); \
  __builtin_amdgcn_s_setprio(0);
#define G256_EDGE(vm_) \
  asm volatile("s_waitcnt vmcnt(" #vm_ ")" ::: "memory"); \
  __builtin_amdgcn_s_barrier(); \
  __builtin_amdgcn_sched_barrier(0);
#define G256_EDGE_NOVM() \
  asm volatile("" ::: "memory"); \
  __builtin_amdgcn_s_barrier(); \
  __builtin_amdgcn_sched_barrier(0);

template <typename OT, bool VTE>
__global__ __launch_bounds__(512, 2) void gemm256_k(const bf16* __restrict__ A, const bf16* __restrict__ BT,
                                                    OT* __restrict__ Cout, int M, int N, int K, int nbx) {
  const int nwg = gridDim.x;
  const int bid = blockIdx.x;
  const int cpx = nwg >> 3;                     // XCD swizzle (nwg%8==0)
  const int swz = (bid & 7) * cpx + (bid >> 3);
  const int bx = swz % nbx, by = swz / nbx;
  const long m0 = (long)by << 8, n0 = (long)bx << 8;

  const int tid = threadIdx.x, w = tid >> 6, l = tid & 63, g = l >> 4, r = l & 15;
  const int wm = w >> 2, wn = w & 3;            // 2 x 4 waves; per-wave C = 128 x 64

  __shared__ __align__(16) char As[2][32768];
  __shared__ __align__(16) char Bs[2][32768];

  long aoff2[4], boff2[4];
  int alds[4], blds[4];
#pragma unroll
  for (int i = 0; i < 4; ++i) {
    int s = i*256 + (tid & 255);
    int ri = s >> 3, c = s & 7, cp = c ^ (ri & 7);
    aoff2[i] = (m0 + wm*128 + ri) * (long)K + cp*8;
    alds[i] = wm*16384 + ((i*256 + (w & 3)*64) << 4);
    int s2 = i*128 + wm*64 + l;
    int ri2 = s2 >> 3, c2 = s2 & 7, cp2 = c2 ^ (ri2 & 7);
    boff2[i] = (n0 + wn*64 + ri2) * (long)K + cp2*8;
    blds[i] = wn*8192 + ((i*128 + wm*64) << 4);
  }

  const f32x4 z4 = {0.f, 0.f, 0.f, 0.f};
  f32x4 acc[8][4];
#pragma unroll
  for (int i = 0; i < 8; ++i)
#pragma unroll
    for (int j = 0; j < 4; ++j) acc[i][j] = z4;

  const int nk = K >> 6;
  gload16(A + aoff2[0], As[0] + alds[0]);
  gload16(A + aoff2[1], As[0] + alds[1]);
  gload16(BT + boff2[0], Bs[0] + blds[0]);
  gload16(BT + boff2[1], Bs[0] + blds[1]);
  gload16(A + aoff2[2], As[0] + alds[2]);
  gload16(A + aoff2[3], As[0] + alds[3]);
  gload16(BT + boff2[2], Bs[0] + blds[2]);
  gload16(BT + boff2[3], Bs[0] + blds[3]);
  G256_EDGE(4);

  bf16x8 af[8], bfr[4];

  for (int t = 0; t < nk - 1; ++t) {
    const int cur = t & 1;
    const char* Ac = As[cur];
    const char* Bc = Bs[cur];
    char* An = As[cur ^ 1];
    char* Bn = Bs[cur ^ 1];
    const long ko = (long)(t + 1) << 6;

    G256_READ_A(0); G256_READ_B(0);
    gload16(A + aoff2[0] + ko, An + alds[0]);
    gload16(A + aoff2[1] + ko, An + alds[1]);
    G256_MFMA(0, 0);
    G256_EDGE(4);

    G256_READ_A(1);
    gload16(BT + boff2[0] + ko, Bn + blds[0]);
    gload16(BT + boff2[1] + ko, Bn + blds[1]);
    G256_MFMA(4, 0);
    G256_EDGE(4);

    G256_READ_B(1);
    gload16(A + aoff2[2] + ko, An + alds[2]);
    gload16(A + aoff2[3] + ko, An + alds[3]);
    G256_MFMA(4, 2);
    G256_EDGE_NOVM();

    G256_READ_A(0);
    gload16(BT + boff2[2] + ko, Bn + blds[2]);
    gload16(BT + boff2[3] + ko, Bn + blds[3]);
    G256_MFMA(0, 2);
    G256_EDGE(4);
  }

  {
    const int cur = (nk - 1) & 1;
    const char* Ac = As[cur];
    const char* Bc = Bs[cur];
    G256_READ_A(0); G256_READ_B(0);
    G256_MFMA(0, 0);
    G256_EDGE(2);
    G256_READ_A(1);
    G256_MFMA(4, 0);
    G256_EDGE(0);
    G256_READ_B(1);
    G256_MFMA(4, 2);
    G256_EDGE_NOVM();
    G256_READ_A(0);
    G256_MFMA(0, 2);
  }

  if (VTE && n0 >= 2*NC) {
#pragma unroll
    for (int mi = 0; mi < 8; ++mi)
#pragma unroll
      for (int ni = 0; ni < 4; ++ni) {
        int d_f = (int)(n0 - 2*NC) + wn*64 + ni*16 + r;    // 0..2047
        long mr = m0 + wm*128 + mi*16 + 4*g;               // j=0 row; j consecutive
        int bb = (int)(mr >> 11), tt = (int)(mr & 2047);
        int hh = d_f >> 7, dd = d_f & 127;
        long rr = (long)(bb*NH + hh)*ND + dd;
        bf16x4 v;
        v[0] = (bf16)acc[mi][ni][0]; v[1] = (bf16)acc[mi][ni][1];
        v[2] = (bf16)acc[mi][ni][2]; v[3] = (bf16)acc[mi][ni][3];
        *(bf16x4*)(Cout + rr*NC3 + 2*NC + tt) = v;
      }
  } else {
#pragma unroll
    for (int mi = 0; mi < 8; ++mi)
#pragma unroll
      for (int ni = 0; ni < 4; ++ni)
#pragma unroll
        for (int j = 0; j < 4; ++j) {
          long mr = m0 + wm*128 + mi*16 + 4*g + j;
          long nc = n0 + wn*64 + ni*16 + r;
          Cout[mr*(long)N + nc] = (OT)acc[mi][ni][j];
        }
  }
}

// ---------------- flash attention (r22 body) + XCD-packed (b,h) grid decode ----------------
// 1-D grid of 1024; xcd=bid&7 picks the XCD (round-robin dispatch); all 16 q-blocks of one
// (b,h) land on the same XCD -> its K/V (1MB) stays L2-resident across them.
__global__ __launch_bounds__(256, 2) void attn_k(const bf16* __restrict__ qkv,
                                                 const char* __restrict__ maskC, bf16* __restrict__ y) {
  const int bid = blockIdx.x;
  const int xcd = bid & 7, idx = bid >> 3;       // idx in [0,128)
  const int hb = xcd*8 + (idx >> 4);             // 8 (b,h) pairs per XCD; bijective over [0,64)
  const int qx = idx & 15;
  const int h = hb & 15, b = hb >> 4;
  const int qb = (qx & 1) ? (15 - (qx >> 1)) : (qx >> 1);   // work-balance remap (bijective)
  const int tid = threadIdx.x, w = tid >> 6, l = tid & 63, g = l >> 4, r = l & 15;
  const int q0 = qb << 7;
  const int bh = b*NH + h;
  const int ntiles = (qb << 1) + 2;
  const int qrowA = q0 + w*32 + r;                // chunk A q-row; chunk B = +16
  const int qrowB = qrowA + 16;

  __shared__ __align__(16) char Klds[2][16384];   // [64 key][128 d], swizzled 16B slots
  __shared__ __align__(16) char Vlds[2][16384];   // [128 d][64 key], swizzled
  __shared__ __align__(16) char Plds[8192];       // per-wave 2KB, shared by both chunks
  __shared__ char Mc[2048];                       // key mask (char) for this b
  char* Pl = Plds + (w << 11);

  for (int i = tid; i < q0 + 128; i += 256) Mc[i] = maskC[b*NT + i];

  long koff[4], voff[4];
  int klo[4];
#pragma unroll
  for (int i = 0; i < 4; ++i) {
    int slot = i*256 + tid;                       // K: 64 rows x 16 slots
    int row = slot >> 4, c = slot & 15, cp = c ^ (row & 7);
    koff[i] = (long)row*NC3 + cp*8;
    klo[i] = (i*256 + w*64) << 4;
    int vrow = slot >> 3, vc = slot & 7, vcp = vc ^ (vrow & 7);   // VT: 128 rows x 8 slots, stride NC3
    voff[i] = (long)vrow*NC3 + vcp*8;
  }
  const bf16* kbase0 = qkv + (long)(b*NT)*NC3 + (NC + h*ND);
  const bf16* vbase0 = qkv + (long)bh*ND*NC3 + 2*NC;   // V^T rows in qkv V third

  bf16x8 qfA[4], qfB[4];
  {
    const bf16* qpA = qkv + (long)(b*NT + qrowA)*NC3 + h*ND + g*8;
    const bf16* qpB = qkv + (long)(b*NT + qrowB)*NC3 + h*ND + g*8;
#pragma unroll
    for (int dk = 0; dk < 4; ++dk) {
      qfA[dk] = *(const bf16x8*)(qpA + dk*32);
      qfB[dk] = *(const bf16x8*)(qpB + dk*32);
    }
  }

  const f32x4 z4 = {0.f, 0.f, 0.f, 0.f};
  f32x4 accA[8], accB[8];
#pragma unroll
  for (int i = 0; i < 8; ++i) { accA[i] = z4; accB[i] = z4; }
  float m_runA = 0.0f, l_runA = 0.0f;   // m init 0: fully-masked rows give p=0 under defer-max
  float m_runB = 0.0f, l_runB = 0.0f;

  const float SCL = 0.08838834764831845f * 1.4426950408889634f;  // 1/sqrt(128) * log2(e)

  // prologue: stage tile 0 into buffer 0
#pragma unroll
  for (int i = 0; i < 4; ++i) {
    gload16(kbase0 + koff[i], Klds[0] + klo[i]);
    gload16(vbase0 + voff[i], Vlds[0] + klo[i]);
  }
  __syncthreads();

  for (int kt = 0; kt < ntiles; ++kt) {
    const int cur = kt & 1;
    if (kt + 1 < ntiles) {
      const bf16* kb = kbase0 + (long)((kt+1)*64)*NC3;
      const bf16* vb = vbase0 + (kt+1)*64;
#pragma unroll
      for (int i = 0; i < 4; ++i) {
        gload16(kb + koff[i], Klds[cur^1] + klo[i]);
        gload16(vb + voff[i], Vlds[cur^1] + klo[i]);
      }
    }
    const char* Kl = Klds[cur];
    const char* Vl = Vlds[cur];
    const int key0 = kt*64;
    const bool actB = (key0 <= q0 + w*32 + 31);    // wave-uniform causal skips
    const bool actA = (key0 <= q0 + w*32 + 15);

    if (actB) {
      u32 mw_[4];
#pragma unroll
      for (int kc = 0; kc < 4; ++kc) mw_[kc] = *(const u32*)(Mc + key0 + kc*16 + 4*g);

      float tvA[4][4], tvB[4][4];
      __builtin_amdgcn_s_setprio(1);
#pragma unroll
      for (int kc = 0; kc < 4; ++kc) {
        const int krow = kc*16 + r;
        bf16x8 kf[4];
#pragma unroll
        for (int dk = 0; dk < 4; ++dk)
          kf[dk] = *(const bf16x8*)(Kl + krow*256 + (((dk*4 + g) ^ (krow & 7)) << 4));
        f32x4 sB = z4;
#pragma unroll
        for (int dk = 0; dk < 4; ++dk)
          sB = __builtin_amdgcn_mfma_f32_16x16x32_bf16(kf[dk], qfB[dk], sB, 0, 0, 0);  // swapped
        f32x4 sA = z4;
        if (actA) {
#pragma unroll
          for (int dk = 0; dk < 4; ++dk)
            sA = __builtin_amdgcn_mfma_f32_16x16x32_bf16(kf[dk], qfA[dk], sA, 0, 0, 0);
        }
#pragma unroll
        for (int j = 0; j < 4; ++j) {
          const int key = key0 + kc*16 + 4*g + j;
          const bool km = ((mw_[kc] >> (8*j)) & 0xffu) != 0;
          tvB[kc][j] = (km && key <= qrowB) ? sB[j]*SCL : -3.0e38f;
          tvA[kc][j] = (km && key <= qrowA) ? sA[j]*SCL : -3.0e38f;
        }
      }
      __builtin_amdgcn_s_setprio(0);

      bf16x8 paA[2], paB[2];
      // ---- chunk A: softmax -> P (shared buffer) -> read paA ----
      if (actA) {
        float tmax = -3.0e38f;
#pragma unroll
        for (int kc = 0; kc < 4; ++kc)
#pragma unroll
          for (int j = 0; j < 4; ++j) tmax = fmaxf(tmax, tvA[kc][j]);
        tmax = fmaxf(tmax, __shfl_xor(tmax, 16));
        tmax = fmaxf(tmax, __shfl_xor(tmax, 32));
        if (!__all(tmax <= m_runA + 8.0f)) {       // defer-max (T13)
          float mn = fmaxf(m_runA, tmax);
          float al = exp2f(m_runA - mn);
          m_runA = mn;
          l_runA *= al;
          float alj[4];
#pragma unroll
          for (int j = 0; j < 4; ++j) alj[j] = __shfl(al, 4*g + j);
#pragma unroll
          for (int d0 = 0; d0 < 8; ++d0)
#pragma unroll
            for (int j = 0; j < 4; ++j) accA[d0][j] *= alj[j];
        }
        float rs = 0.f;
#pragma unroll
        for (int kc = 0; kc < 4; ++kc) {
          float p0 = exp2f(tvA[kc][0] - m_runA), p1 = exp2f(tvA[kc][1] - m_runA);
          float p2 = exp2f(tvA[kc][2] - m_runA), p3 = exp2f(tvA[kc][3] - m_runA);
          rs += (p0 + p1) + (p2 + p3);
          const int off = (kc*32 + g*8) ^ ((r & 7) << 4);
          uint2 wv; wv.x = pack_bf16(p0, p1); wv.y = pack_bf16(p2, p3);
          *(uint2*)(Pl + r*128 + off) = wv;
        }
        rs += __shfl_xor(rs, 16);
        rs += __shfl_xor(rs, 32);
        l_runA += rs;
        // P write -> read fence (rule #18)
        asm volatile("s_waitcnt lgkmcnt(0)" ::: "memory");
        __builtin_amdgcn_sched_barrier(0);
#pragma unroll
        for (int kk = 0; kk < 2; ++kk)
          paA[kk] = *(const bf16x8*)(Pl + r*128 + ((kk*64 + g*16) ^ ((r & 7) << 4)));
        // HW DS in-order per wave: reads ordered before chunk B's writes; pin compiler only.
        __builtin_amdgcn_sched_barrier(0);
      }
      // ---- chunk B: softmax -> P (same buffer) -> read paB ----
      {
        float tmax = -3.0e38f;
#pragma unroll
        for (int kc = 0; kc < 4; ++kc)
#pragma unroll
          for (int j = 0; j < 4; ++j) tmax = fmaxf(tmax, tvB[kc][j]);
        tmax = fmaxf(tmax, __shfl_xor(tmax, 16));
        tmax = fmaxf(tmax, __shfl_xor(tmax, 32));
        if (!__all(tmax <= m_runB + 8.0f)) {
          float mn = fmaxf(m_runB, tmax);
          float al = exp2f(m_runB - mn);
          m_runB = mn;
          l_runB *= al;
          float alj[4];
#pragma unroll
          for (int j = 0; j < 4; ++j) alj[j] = __shfl(al, 4*g + j);
#pragma unroll
          for (int d0 = 0; d0 < 8; ++d0)
#pragma unroll
            for (int j = 0; j < 4; ++j) accB[d0][j] *= alj[j];
        }
        float rs = 0.f;
#pragma unroll
        for (int kc = 0; kc < 4; ++kc) {
          float p0 = exp2f(tvB[kc][0] - m_runB), p1 = exp2f(tvB[kc][1] - m_runB);
          float p2 = exp2f(tvB[kc][2] - m_runB), p3 = exp2f(tvB[kc][3] - m_runB);
          rs += (p0 + p1) + (p2 + p3);
          const int off = (kc*32 + g*8) ^ ((r & 7) << 4);
          uint2 wv; wv.x = pack_bf16(p0, p1); wv.y = pack_bf16(p2, p3);
          *(uint2*)(Pl + r*128 + off) = wv;
        }
        rs += __shfl_xor(rs, 16);
        rs += __shfl_xor(rs, 32);
        l_runB += rs;
        asm volatile("s_waitcnt lgkmcnt(0)" ::: "memory");
        __builtin_amdgcn_sched_barrier(0);
#pragma unroll
        for (int kk = 0; kk < 2; ++kk)
          paB[kk] = *(const bf16x8*)(Pl + r*128 + ((kk*64 + g*16) ^ ((r & 7) << 4)));
      }

      // ---- fused PV: V frags shared by both chunks ----
      __builtin_amdgcn_s_setprio(1);
#pragma unroll
      for (int d0 = 0; d0 < 8; ++d0) {
        const int vrow = d0*16 + r;
#pragma unroll
        for (int kk = 0; kk < 2; ++kk) {
          bf16x8 vf = *(const bf16x8*)(Vl + vrow*128 + (((kk*4 + g) ^ (vrow & 7)) << 4));
          accB[d0] = __builtin_amdgcn_mfma_f32_16x16x32_bf16(paB[kk], vf, accB[d0], 0, 0, 0);
          if (actA) accA[d0] = __builtin_amdgcn_mfma_f32_16x16x32_bf16(paA[kk], vf, accA[d0], 0, 0, 0);
        }
      }
      __builtin_amdgcn_s_setprio(0);
    }
    __syncthreads();   // next-tile stage complete + guards K/V/P buffer reuse
  }

  // epilogue: normalize both chunks; acc rows are q=4g+j, l_run lives at lanes r'=4g+j
  {
    float lrA[4], lrB[4];
#pragma unroll
    for (int j = 0; j < 4; ++j) {
      lrA[j] = __shfl(l_runA, 4*g + j);
      lrB[j] = __shfl(l_runB, 4*g + j);
    }
#pragma unroll
    for (int d0 = 0; d0 < 8; ++d0)
#pragma unroll
      for (int j = 0; j < 4; ++j) {
        int qrA = q0 + w*32 + 4*g + j;
        y[(long)(b*NT + qrA)*NC + h*ND + d0*16 + r] = (bf16)(accA[d0][j] / lrA[j]);
        y[(long)(b*NT + qrA + 16)*NC + h*ND + d0*16 + r] = (bf16)(accB[d0][j] / lrB[j]);
      }
  }
}

extern "C" void kernel_launch(void* const* d_in, const int* in_sizes, int n_in,
                              void* d_out, int out_size, void* d_ws, size_t ws_size,
                              hipStream_t stream) {
  const float* xr     = (const float*)d_in[0];   // f32 inputs (round-6 proven)
  const void*  tok    = d_in[1];
  const float* wqkvr  = (const float*)d_in[2];
  const float* wprojr = (const float*)d_in[3];
  float* out = (float*)d_out;                    // f32 output
  char* ws = (char*)d_ws;

  bf16* qkv    = (bf16*)(ws);                       // 100,663,296 B (V third holds V^T rows)
  bf16* yattn  = (bf16*)(ws + 100663296L);          //  33,554,432 B
  bf16* wT     = (bf16*)(ws + 134217728L);          //  25,165,824 B  W_qkv^T
  bf16* wpT    = (bf16*)(ws + 159383552L);          //   8,388,608 B  W_proj^T
  bf16* xb     = (bf16*)(ws + 167772160L);          //  33,554,432 B  bf16 x
  char* maskC  = (char*)(ws + 201326592L);          //       8,192 B

  // merged prep: mask | x ingest | W_qkv^T | W_proj^T  (grid = 1 + 8192 + 3072 + 1024)
  prep_k<<<12289, 256, 0, stream>>>(tok, maskC, xr, xb, wqkvr, wT, wprojr, wpT);
  // qkv = x @ W_qkv; V third written transposed in-place (grid = 24*32 = 768)
  gemm256_k<bf16, true><<<768, 512, 0, stream>>>(xb, wT, qkv, 8192, 6144, 2048, 24);
  // attention (XCD-packed (b,h) decode; 1-D grid of 1024)
  attn_k<<<1024, 256, 0, stream>>>(qkv, maskC, yattn);
  // out = y @ W_proj  (f32 output; grid = 8*32 = 256)
  gemm256_k<float, false><<<256, 512, 0, stream>>>(yattn, wpT, out, 8192, 2048, 2048, 8);
}

// Round 24
// 511.408 us; speedup vs baseline: 18.5102x; 18.5102x over previous
//
#include <hip/hip_runtime.h>
#include <hip/hip_bf16.h>
#include <stdint.h>

typedef __bf16 bf16;
typedef __bf16 bf16x8 __attribute__((ext_vector_type(8)));
typedef __bf16 bf16x4 __attribute__((ext_vector_type(4)));
typedef float f32x4 __attribute__((ext_vector_type(4)));
typedef unsigned short u16;
typedef unsigned int u32;

constexpr int NB = 4;
constexpr int NT = 2048;
constexpr int NC = 2048;
constexpr int NH = 16;
constexpr int ND = 128;
constexpr int NC3 = 6144;

__device__ __forceinline__ void gload16(const void* g, void* l) {
  __builtin_amdgcn_global_load_lds((const __attribute__((address_space(1))) void*)g,
                                   (__attribute__((address_space(3))) void*)l, 16, 0, 0);
}

__device__ __forceinline__ u32 pack_bf16(float a, float b) {
  return (u32)__builtin_bit_cast(u16, (bf16)a) | ((u32)__builtin_bit_cast(u16, (bf16)b) << 16);
}

// ---------------- merged prep: mask decode | x ingest | W_qkv^T | W_proj^T ----------------
__global__ __launch_bounds__(256) void prep_k(const void* tok, char* maskC,
                                              const float* __restrict__ xr, bf16* __restrict__ xb,
                                              const float* __restrict__ wqkvr, bf16* __restrict__ wT,
                                              const float* __restrict__ wprojr, bf16* __restrict__ wpT) {
  __shared__ __align__(16) bf16 t[64][72];
  __shared__ int s_gt1, s_oddnz, s_allb, s_allf, s_allh;
  const int gid = blockIdx.x;
  const int tid = threadIdx.x;

  if (gid == 0) {
    if (tid == 0) { s_gt1 = 0; s_oddnz = 0; s_allb = 1; s_allf = 1; s_allh = 1; }
    __syncthreads();
    const unsigned int* mw = (const unsigned int*)tok;
    int gt1 = 0, oddnz = 0, allb = 1, allf = 1, allh = 1;
    for (int i = tid; i < 2048; i += 256) {
      unsigned v = mw[i];
      if (v > 1u) gt1 = 1;
      if ((i & 1) && v) oddnz = 1;
#pragma unroll
      for (int bb = 0; bb < 4; ++bb) { unsigned by = (v >> (8*bb)) & 0xffu; if (by > 1u) allb = 0; }
      if (v != 0u && v != 0x3F800000u) allf = 0;
      unsigned lo = v & 0xffffu, hi = v >> 16;
      if ((lo != 0u && lo != 0x3F80u) || (hi != 0u && hi != 0x3F80u)) allh = 0;
    }
    if (gt1) atomicOr(&s_gt1, 1);
    if (oddnz) atomicOr(&s_oddnz, 1);
    if (!allb) atomicAnd(&s_allb, 0);
    if (!allf) atomicAnd(&s_allf, 0);
    if (!allh) atomicAnd(&s_allh, 0);
    __syncthreads();
    int mode;
    if (!s_gt1)       mode = s_oddnz ? 0 : 2;
    else if (s_allf)  mode = 3;
    else if (s_allb)  mode = 1;
    else if (s_allh)  mode = 4;
    else              mode = 0;
    for (int i = tid; i < NB*NT; i += 256) {
      int v;
      if (mode == 0)      v = (((const int*)tok)[i] != 0);
      else if (mode == 1) v = (((const unsigned char*)tok)[i] != 0);
      else if (mode == 2) v = (((const long long*)tok)[i] != 0);
      else if (mode == 3) v = (((const unsigned int*)tok)[i] != 0);
      else                v = (((const unsigned short*)tok)[i] != 0);
      maskC[i] = (char)v;
    }
  } else if (gid < 8193) {
    long i = ((long)(gid - 1) * 256 + tid) * 8;
    f32x4 a = *(const f32x4*)(xr + i), b = *(const f32x4*)(xr + i + 4);
    bf16x8 o;
    o[0] = (bf16)a[0]; o[1] = (bf16)a[1]; o[2] = (bf16)a[2]; o[3] = (bf16)a[3];
    o[4] = (bf16)b[0]; o[5] = (bf16)b[1]; o[6] = (bf16)b[2]; o[7] = (bf16)b[3];
    *(bf16x8*)(xb + i) = o;
  } else {
    const float* in; bf16* out; int in_rs, out_rs, bx, by;
    if (gid < 11265) { int idx = gid - 8193; in = wqkvr; out = wT;  in_rs = NC3; out_rs = NC; bx = idx % 96; by = idx / 96; }
    else             { int idx = gid - 11265; in = wprojr; out = wpT; in_rs = NC;  out_rs = NC; bx = idx % 32; by = idx / 32; }
    const int r0 = by << 6, c0 = bx << 6;
#pragma unroll
    for (int i = 0; i < 4; ++i) {
      int slot = i*256 + tid, row = slot >> 4, c4 = slot & 15;
      f32x4 v = *(const f32x4*)(in + (long)(r0 + row)*in_rs + c0 + c4*4);
#pragma unroll
      for (int e = 0; e < 4; ++e) t[c4*4 + e][row] = (bf16)v[e];
    }
    __syncthreads();
#pragma unroll
    for (int i = 0; i < 2; ++i) {
      int slot = i*256 + tid, row = slot >> 3, c8 = slot & 7;
      bf16x8 v = *(const bf16x8*)(&t[row][c8*8]);
      *(bf16x8*)(out + (long)(c0 + row)*out_rs + r0 + c8*8) = v;
    }
  }
}

// ---------------- GEMM 256x256, 8 waves, 4-phase, spread-staged counted-vmcnt pipeline (r22) ----------------
#define G256_READ_A(qm_) \
  _Pragma("unroll") \
  for (int mi = 0; mi < 4; ++mi) { \
    _Pragma("unroll") \
    for (int kk = 0; kk < 2; ++kk) { \
      const int ri = (qm_)*64 + mi*16 + r; \
      af[mi*2+kk] = *(const bf16x8*)(Ac + wm*16384 + ri*128 + (((kk*4 + g) ^ (ri & 7)) << 4)); \
    } \
  }
#define G256_READ_B(qn_) \
  _Pragma("unroll") \
  for (int ni = 0; ni < 2; ++ni) { \
    _Pragma("unroll") \
    for (int kk = 0; kk < 2; ++kk) { \
      const int ri = (qn_)*32 + ni*16 + r; \
      bfr[ni*2+kk] = *(const bf16x8*)(Bc + wn*8192 + ri*128 + (((kk*4 + g) ^ (ri & 7)) << 4)); \
    } \
  }
#define G256_MFMA(mb_, nb_) \
  __builtin_amdgcn_s_setprio(1); \
  _Pragma("unroll") \
  for (int mi = 0; mi < 4; ++mi) \
    _Pragma("unroll") \
    for (int ni = 0; ni < 2; ++ni) \
      _Pragma("unroll") \
      for (int kk = 0; kk < 2; ++kk) \
        acc[(mb_)+mi][(nb_)+ni] = __builtin_amdgcn_mfma_f32_16x16x32_bf16(af[mi*2+kk], bfr[ni*2+kk], acc[(mb_)+mi][(nb_)+ni], 0, 0, 0); \
  __builtin_amdgcn_s_setprio(0);
#define G256_EDGE(vm_) \
  asm volatile("s_waitcnt vmcnt(" #vm_ ")" ::: "memory"); \
  __builtin_amdgcn_s_barrier(); \
  __builtin_amdgcn_sched_barrier(0);
#define G256_EDGE_NOVM() \
  asm volatile("" ::: "memory"); \
  __builtin_amdgcn_s_barrier(); \
  __builtin_amdgcn_sched_barrier(0);

template <typename OT, bool VTE>
__global__ __launch_bounds__(512, 2) void gemm256_k(const bf16* __restrict__ A, const bf16* __restrict__ BT,
                                                    OT* __restrict__ Cout, int M, int N, int K, int nbx) {
  const int nwg = gridDim.x;
  const int bid = blockIdx.x;
  const int cpx = nwg >> 3;                     // XCD swizzle (nwg%8==0)
  const int swz = (bid & 7) * cpx + (bid >> 3);
  const int bx = swz % nbx, by = swz / nbx;
  const long m0 = (long)by << 8, n0 = (long)bx << 8;

  const int tid = threadIdx.x, w = tid >> 6, l = tid & 63, g = l >> 4, r = l & 15;
  const int wm = w >> 2, wn = w & 3;            // 2 x 4 waves; per-wave C = 128 x 64

  __shared__ __align__(16) char As[2][32768];
  __shared__ __align__(16) char Bs[2][32768];

  long aoff2[4], boff2[4];
  int alds[4], blds[4];
#pragma unroll
  for (int i = 0; i < 4; ++i) {
    int s = i*256 + (tid & 255);
    int ri = s >> 3, c = s & 7, cp = c ^ (ri & 7);
    aoff2[i] = (m0 + wm*128 + ri) * (long)K + cp*8;
    alds[i] = wm*16384 + ((i*256 + (w & 3)*64) << 4);
    int s2 = i*128 + wm*64 + l;
    int ri2 = s2 >> 3, c2 = s2 & 7, cp2 = c2 ^ (ri2 & 7);
    boff2[i] = (n0 + wn*64 + ri2) * (long)K + cp2*8;
    blds[i] = wn*8192 + ((i*128 + wm*64) << 4);
  }

  const f32x4 z4 = {0.f, 0.f, 0.f, 0.f};
  f32x4 acc[8][4];
#pragma unroll
  for (int i = 0; i < 8; ++i)
#pragma unroll
    for (int j = 0; j < 4; ++j) acc[i][j] = z4;

  const int nk = K >> 6;
  gload16(A + aoff2[0], As[0] + alds[0]);
  gload16(A + aoff2[1], As[0] + alds[1]);
  gload16(BT + boff2[0], Bs[0] + blds[0]);
  gload16(BT + boff2[1], Bs[0] + blds[1]);
  gload16(A + aoff2[2], As[0] + alds[2]);
  gload16(A + aoff2[3], As[0] + alds[3]);
  gload16(BT + boff2[2], Bs[0] + blds[2]);
  gload16(BT + boff2[3], Bs[0] + blds[3]);
  G256_EDGE(4);

  bf16x8 af[8], bfr[4];

  for (int t = 0; t < nk - 1; ++t) {
    const int cur = t & 1;
    const char* Ac = As[cur];
    const char* Bc = Bs[cur];
    char* An = As[cur ^ 1];
    char* Bn = Bs[cur ^ 1];
    const long ko = (long)(t + 1) << 6;

    G256_READ_A(0); G256_READ_B(0);
    gload16(A + aoff2[0] + ko, An + alds[0]);
    gload16(A + aoff2[1] + ko, An + alds[1]);
    G256_MFMA(0, 0);
    G256_EDGE(4);

    G256_READ_A(1);
    gload16(BT + boff2[0] + ko, Bn + blds[0]);
    gload16(BT + boff2[1] + ko, Bn + blds[1]);
    G256_MFMA(4, 0);
    G256_EDGE(4);

    G256_READ_B(1);
    gload16(A + aoff2[2] + ko, An + alds[2]);
    gload16(A + aoff2[3] + ko, An + alds[3]);
    G256_MFMA(4, 2);
    G256_EDGE_NOVM();

    G256_READ_A(0);
    gload16(BT + boff2[2] + ko, Bn + blds[2]);
    gload16(BT + boff2[3] + ko, Bn + blds[3]);
    G256_MFMA(0, 2);
    G256_EDGE(4);
  }

  {
    const int cur = (nk - 1) & 1;
    const char* Ac = As[cur];
    const char* Bc = Bs[cur];
    G256_READ_A(0); G256_READ_B(0);
    G256_MFMA(0, 0);
    G256_EDGE(2);
    G256_READ_A(1);
    G256_MFMA(4, 0);
    G256_EDGE(0);
    G256_READ_B(1);
    G256_MFMA(4, 2);
    G256_EDGE_NOVM();
    G256_READ_A(0);
    G256_MFMA(0, 2);
  }

  if (VTE && n0 >= 2*NC) {
#pragma unroll
    for (int mi = 0; mi < 8; ++mi)
#pragma unroll
      for (int ni = 0; ni < 4; ++ni) {
        int d_f = (int)(n0 - 2*NC) + wn*64 + ni*16 + r;    // 0..2047
        long mr = m0 + wm*128 + mi*16 + 4*g;               // j=0 row; j consecutive
        int bb = (int)(mr >> 11), tt = (int)(mr & 2047);
        int hh = d_f >> 7, dd = d_f & 127;
        long rr = (long)(bb*NH + hh)*ND + dd;
        bf16x4 v;
        v[0] = (bf16)acc[mi][ni][0]; v[1] = (bf16)acc[mi][ni][1];
        v[2] = (bf16)acc[mi][ni][2]; v[3] = (bf16)acc[mi][ni][3];
        *(bf16x4*)(Cout + rr*NC3 + 2*NC + tt) = v;
      }
  } else {
#pragma unroll
    for (int mi = 0; mi < 8; ++mi)
#pragma unroll
      for (int ni = 0; ni < 4; ++ni)
#pragma unroll
        for (int j = 0; j < 4; ++j) {
          long mr = m0 + wm*128 + mi*16 + 4*g + j;
          long nc = n0 + wn*64 + ni*16 + r;
          Cout[mr*(long)N + nc] = (OT)acc[mi][ni][j];
        }
  }
}

// ---------------- flash attention (r13/r17 structure; r22 fence trim; best measured ~247us) ----------------
__global__ __launch_bounds__(256, 2) void attn_k(const bf16* __restrict__ qkv,
                                                 const char* __restrict__ maskC, bf16* __restrict__ y) {
  const int qx = blockIdx.x, h = blockIdx.y, b = blockIdx.z;
  const int qb = (qx & 1) ? (15 - (qx >> 1)) : (qx >> 1);   // work-balance remap (bijective)
  const int tid = threadIdx.x, w = tid >> 6, l = tid & 63, g = l >> 4, r = l & 15;
  const int q0 = qb << 7;
  const int bh = b*NH + h;
  const int ntiles = (qb << 1) + 2;
  const int qrowA = q0 + w*32 + r;                // chunk A q-row; chunk B = +16
  const int qrowB = qrowA + 16;

  __shared__ __align__(16) char Klds[2][16384];   // [64 key][128 d], swizzled 16B slots
  __shared__ __align__(16) char Vlds[2][16384];   // [128 d][64 key], swizzled
  __shared__ __align__(16) char Plds[8192];       // per-wave 2KB, shared by both chunks
  __shared__ char Mc[2048];                       // key mask (char) for this b
  char* Pl = Plds + (w << 11);

  for (int i = tid; i < q0 + 128; i += 256) Mc[i] = maskC[b*NT + i];

  long koff[4], voff[4];
  int klo[4];
#pragma unroll
  for (int i = 0; i < 4; ++i) {
    int slot = i*256 + tid;                       // K: 64 rows x 16 slots
    int row = slot >> 4, c = slot & 15, cp = c ^ (row & 7);
    koff[i] = (long)row*NC3 + cp*8;
    klo[i] = (i*256 + w*64) << 4;
    int vrow = slot >> 3, vc = slot & 7, vcp = vc ^ (vrow & 7);   // VT: 128 rows x 8 slots, stride NC3
    voff[i] = (long)vrow*NC3 + vcp*8;
  }
  const bf16* kbase0 = qkv + (long)(b*NT)*NC3 + (NC + h*ND);
  const bf16* vbase0 = qkv + (long)bh*ND*NC3 + 2*NC;   // V^T rows in qkv V third

  bf16x8 qfA[4], qfB[4];
  {
    const bf16* qpA = qkv + (long)(b*NT + qrowA)*NC3 + h*ND + g*8;
    const bf16* qpB = qkv + (long)(b*NT + qrowB)*NC3 + h*ND + g*8;
#pragma unroll
    for (int dk = 0; dk < 4; ++dk) {
      qfA[dk] = *(const bf16x8*)(qpA + dk*32);
      qfB[dk] = *(const bf16x8*)(qpB + dk*32);
    }
  }

  const f32x4 z4 = {0.f, 0.f, 0.f, 0.f};
  f32x4 accA[8], accB[8];
#pragma unroll
  for (int i = 0; i < 8; ++i) { accA[i] = z4; accB[i] = z4; }
  float m_runA = 0.0f, l_runA = 0.0f;   // m init 0: fully-masked rows give p=0 under defer-max
  float m_runB = 0.0f, l_runB = 0.0f;

  const float SCL = 0.08838834764831845f * 1.4426950408889634f;  // 1/sqrt(128) * log2(e)

  // prologue: stage tile 0 into buffer 0
#pragma unroll
  for (int i = 0; i < 4; ++i) {
    gload16(kbase0 + koff[i], Klds[0] + klo[i]);
    gload16(vbase0 + voff[i], Vlds[0] + klo[i]);
  }
  __syncthreads();

  for (int kt = 0; kt < ntiles; ++kt) {
    const int cur = kt & 1;
    if (kt + 1 < ntiles) {
      const bf16* kb = kbase0 + (long)((kt+1)*64)*NC3;
      const bf16* vb = vbase0 + (kt+1)*64;
#pragma unroll
      for (int i = 0; i < 4; ++i) {
        gload16(kb + koff[i], Klds[cur^1] + klo[i]);
        gload16(vb + voff[i], Vlds[cur^1] + klo[i]);
      }
    }
    const char* Kl = Klds[cur];
    const char* Vl = Vlds[cur];
    const int key0 = kt*64;
    const bool actB = (key0 <= q0 + w*32 + 31);    // wave-uniform causal skips
    const bool actA = (key0 <= q0 + w*32 + 15);

    if (actB) {
      u32 mw_[4];
#pragma unroll
      for (int kc = 0; kc < 4; ++kc) mw_[kc] = *(const u32*)(Mc + key0 + kc*16 + 4*g);

      float tvA[4][4], tvB[4][4];
      __builtin_amdgcn_s_setprio(1);
#pragma unroll
      for (int kc = 0; kc < 4; ++kc) {
        const int krow = kc*16 + r;
        bf16x8 kf[4];
#pragma unroll
        for (int dk = 0; dk < 4; ++dk)
          kf[dk] = *(const bf16x8*)(Kl + krow*256 + (((dk*4 + g) ^ (krow & 7)) << 4));
        f32x4 sB = z4;
#pragma unroll
        for (int dk = 0; dk < 4; ++dk)
          sB = __builtin_amdgcn_mfma_f32_16x16x32_bf16(kf[dk], qfB[dk], sB, 0, 0, 0);  // swapped
        f32x4 sA = z4;
        if (actA) {
#pragma unroll
          for (int dk = 0; dk < 4; ++dk)
            sA = __builtin_amdgcn_mfma_f32_16x16x32_bf16(kf[dk], qfA[dk], sA, 0, 0, 0);
        }
#pragma unroll
        for (int j = 0; j < 4; ++j) {
          const int key = key0 + kc*16 + 4*g + j;
          const bool km = ((mw_[kc] >> (8*j)) & 0xffu) != 0;
          tvB[kc][j] = (km && key <= qrowB) ? sB[j]*SCL : -3.0e38f;
          tvA[kc][j] = (km && key <= qrowA) ? sA[j]*SCL : -3.0e38f;
        }
      }
      __builtin_amdgcn_s_setprio(0);

      bf16x8 paA[2], paB[2];
      // ---- chunk A: softmax -> P (shared buffer) -> read paA ----
      if (actA) {
        float tmax = -3.0e38f;
#pragma unroll
        for (int kc = 0; kc < 4; ++kc)
#pragma unroll
          for (int j = 0; j < 4; ++j) tmax = fmaxf(tmax, tvA[kc][j]);
        tmax = fmaxf(tmax, __shfl_xor(tmax, 16));
        tmax = fmaxf(tmax, __shfl_xor(tmax, 32));
        if (!__all(tmax <= m_runA + 8.0f)) {       // defer-max (T13)
          float mn = fmaxf(m_runA, tmax);
          float al = exp2f(m_runA - mn);
          m_runA = mn;
          l_runA *= al;
          float alj[4];
#pragma unroll
          for (int j = 0; j < 4; ++j) alj[j] = __shfl(al, 4*g + j);
#pragma unroll
          for (int d0 = 0; d0 < 8; ++d0)
#pragma unroll
            for (int j = 0; j < 4; ++j) accA[d0][j] *= alj[j];
        }
        float rs = 0.f;
#pragma unroll
        for (int kc = 0; kc < 4; ++kc) {
          float p0 = exp2f(tvA[kc][0] - m_runA), p1 = exp2f(tvA[kc][1] - m_runA);
          float p2 = exp2f(tvA[kc][2] - m_runA), p3 = exp2f(tvA[kc][3] - m_runA);
          rs += (p0 + p1) + (p2 + p3);
          const int off = (kc*32 + g*8) ^ ((r & 7) << 4);
          uint2 wv; wv.x = pack_bf16(p0, p1); wv.y = pack_bf16(p2, p3);
          *(uint2*)(Pl + r*128 + off) = wv;
        }
        rs += __shfl_xor(rs, 16);
        rs += __shfl_xor(rs, 32);
        l_runA += rs;
        // P write -> read fence (rule #18)
        asm volatile("s_waitcnt lgkmcnt(0)" ::: "memory");
        __builtin_amdgcn_sched_barrier(0);
#pragma unroll
        for (int kk = 0; kk < 2; ++kk)
          paA[kk] = *(const bf16x8*)(Pl + r*128 + ((kk*64 + g*16) ^ ((r & 7) << 4)));
        // HW DS in-order per wave: reads ordered before chunk B's writes; pin compiler only.
        __builtin_amdgcn_sched_barrier(0);
      }
      // ---- chunk B: softmax -> P (same buffer) -> read paB ----
      {
        float tmax = -3.0e38f;
#pragma unroll
        for (int kc = 0; kc < 4; ++kc)
#pragma unroll
          for (int j = 0; j < 4; ++j) tmax = fmaxf(tmax, tvB[kc][j]);
        tmax = fmaxf(tmax, __shfl_xor(tmax, 16));
        tmax = fmaxf(tmax, __shfl_xor(tmax, 32));
        if (!__all(tmax <= m_runB + 8.0f)) {
          float mn = fmaxf(m_runB, tmax);
          float al = exp2f(m_runB - mn);
          m_runB = mn;
          l_runB *= al;
          float alj[4];
#pragma unroll
          for (int j = 0; j < 4; ++j) alj[j] = __shfl(al, 4*g + j);
#pragma unroll
          for (int d0 = 0; d0 < 8; ++d0)
#pragma unroll
            for (int j = 0; j < 4; ++j) accB[d0][j] *= alj[j];
        }
        float rs = 0.f;
#pragma unroll
        for (int kc = 0; kc < 4; ++kc) {
          float p0 = exp2f(tvB[kc][0] - m_runB), p1 = exp2f(tvB[kc][1] - m_runB);
          float p2 = exp2f(tvB[kc][2] - m_runB), p3 = exp2f(tvB[kc][3] - m_runB);
          rs += (p0 + p1) + (p2 + p3);
          const int off = (kc*32 + g*8) ^ ((r & 7) << 4);
          uint2 wv; wv.x = pack_bf16(p0, p1); wv.y = pack_bf16(p2, p3);
          *(uint2*)(Pl + r*128 + off) = wv;
        }
        rs += __shfl_xor(rs, 16);
        rs += __shfl_xor(rs, 32);
        l_runB += rs;
        asm volatile("s_waitcnt lgkmcnt(0)" ::: "memory");
        __builtin_amdgcn_sched_barrier(0);
#pragma unroll
        for (int kk = 0; kk < 2; ++kk)
          paB[kk] = *(const bf16x8*)(Pl + r*128 + ((kk*64 + g*16) ^ ((r & 7) << 4)));
      }

      // ---- fused PV: V frags shared by both chunks ----
      __builtin_amdgcn_s_setprio(1);
#pragma unroll
      for (int d0 = 0; d0 < 8; ++d0) {
        const int vrow = d0*16 + r;
#pragma unroll
        for (int kk = 0; kk < 2; ++kk) {
          bf16x8 vf = *(const bf16x8*)(Vl + vrow*128 + (((kk*4 + g) ^ (vrow & 7)) << 4));
          accB[d0] = __builtin_amdgcn_mfma_f32_16x16x32_bf16(paB[kk], vf, accB[d0], 0, 0, 0);
          if (actA) accA[d0] = __builtin_amdgcn_mfma_f32_16x16x32_bf16(paA[kk], vf, accA[d0], 0, 0, 0);
        }
      }
      __builtin_amdgcn_s_setprio(0);
    }
    __syncthreads();   // next-tile stage complete + guards K/V/P buffer reuse
  }

  // epilogue: normalize both chunks; acc rows are q=4g+j, l_run lives at lanes r'=4g+j
  {
    float lrA[4], lrB[4];
#pragma unroll
    for (int j = 0; j < 4; ++j) {
      lrA[j] = __shfl(l_runA, 4*g + j);
      lrB[j] = __shfl(l_runB, 4*g + j);
    }
#pragma unroll
    for (int d0 = 0; d0 < 8; ++d0)
#pragma unroll
      for (int j = 0; j < 4; ++j) {
        int qrA = q0 + w*32 + 4*g + j;
        y[(long)(b*NT + qrA)*NC + h*ND + d0*16 + r] = (bf16)(accA[d0][j] / lrA[j]);
        y[(long)(b*NT + qrA + 16)*NC + h*ND + d0*16 + r] = (bf16)(accB[d0][j] / lrB[j]);
      }
  }
}

extern "C" void kernel_launch(void* const* d_in, const int* in_sizes, int n_in,
                              void* d_out, int out_size, void* d_ws, size_t ws_size,
                              hipStream_t stream) {
  const float* xr     = (const float*)d_in[0];   // f32 inputs (round-6 proven)
  const void*  tok    = d_in[1];
  const float* wqkvr  = (const float*)d_in[2];
  const float* wprojr = (const float*)d_in[3];
  float* out = (float*)d_out;                    // f32 output
  char* ws = (char*)d_ws;

  bf16* qkv    = (bf16*)(ws);                       // 100,663,296 B (V third holds V^T rows)
  bf16* yattn  = (bf16*)(ws + 100663296L);          //  33,554,432 B
  bf16* wT     = (bf16*)(ws + 134217728L);          //  25,165,824 B  W_qkv^T
  bf16* wpT    = (bf16*)(ws + 159383552L);          //   8,388,608 B  W_proj^T
  bf16* xb     = (bf16*)(ws + 167772160L);          //  33,554,432 B  bf16 x
  char* maskC  = (char*)(ws + 201326592L);          //       8,192 B

  // merged prep: mask | x ingest | W_qkv^T | W_proj^T  (grid = 1 + 8192 + 3072 + 1024)
  prep_k<<<12289, 256, 0, stream>>>(tok, maskC, xr, xb, wqkvr, wT, wprojr, wpT);
  // qkv = x @ W_qkv; V third written transposed in-place (grid = 24*32 = 768)
  gemm256_k<bf16, true><<<768, 512, 0, stream>>>(xb, wT, qkv, 8192, 6144, 2048, 24);
  // attention (r13/r17 structure; V from qkv's V third)
  attn_k<<<dim3(16, 16, 4), 256, 0, stream>>>(qkv, maskC, yattn);
  // out = y @ W_proj  (f32 output; grid = 8*32 = 256)
  gemm256_k<float, false><<<256, 512, 0, stream>>>(yattn, wpT, out, 8192, 2048, 2048, 8);
}